// Round 1
// baseline (110.656 us; speedup 1.0000x reference)
//
#include <hip/hip_runtime.h>

constexpr int FEAT = 512;          // feature dim
constexpr int NCLS = 50000;        // classes
constexpr int B    = 8192;         // batch
constexpr float ALPHA_F = 0.1f;

// ---------------------------------------------------------------------------
// ws layout: [0, NCLS) f32 counts | [NCLS, NCLS+B) f32 per-row loss partials
// ---------------------------------------------------------------------------

__global__ void k_count(const int* __restrict__ labels,
                        float* __restrict__ counts) {
    int i = blockIdx.x * blockDim.x + threadIdx.x;
    if (i < B) atomicAdd(&counts[labels[i]], 1.0f);
}

// new_centers = centers * (count>0 ? (1-alpha) : 1)
// scalar dword stores because out_centers = d_out+1 (misaligned for float4)
__global__ void k_base(const float* __restrict__ centers,
                       const float* __restrict__ counts,
                       float* __restrict__ outc) {
    const long long total  = (long long)NCLS * FEAT;     // 25.6M
    const long long stride = (long long)gridDim.x * blockDim.x;
    for (long long i = (long long)blockIdx.x * blockDim.x + threadIdx.x;
         i < total; i += stride) {
        int cls = (int)(i >> 9);                          // /FEAT (512)
        float scale = (counts[cls] > 0.0f) ? (1.0f - ALPHA_F) : 1.0f;
        outc[i] = centers[i] * scale;
    }
}

// One wave (64 lanes) per batch row:
//   loss partial: sum_d (f-c)^2  -> shuffle reduce -> partials[row]
//   scatter:      new_centers[label][d] += (alpha/count) * f[d]
__global__ void k_row(const float* __restrict__ features,
                      const int* __restrict__ labels,
                      const float* __restrict__ centers,
                      const float* __restrict__ counts,
                      float* __restrict__ outc,
                      float* __restrict__ partials) {
    const int row  = blockIdx.x;      // B blocks
    const int lane = threadIdx.x;     // 64 threads
    const int lbl  = labels[row];

    const float4* f4 = (const float4*)(features + (long long)row * FEAT);
    const float4* c4 = (const float4*)(centers  + (long long)lbl * FEAT);
    float*        oc = outc + (long long)lbl * FEAT;
    const float   inv = ALPHA_F / counts[lbl];   // count >= 1 (label present)

    float loss = 0.0f;
#pragma unroll
    for (int k = 0; k < 2; ++k) {                 // 128 float4 over 64 lanes
        const int idx = lane + k * 64;
        const float4 f = f4[idx];
        const float4 c = c4[idx];
        const float dx = f.x - c.x, dy = f.y - c.y,
                    dz = f.z - c.z, dw = f.w - c.w;
        loss += dx*dx + dy*dy + dz*dz + dw*dw;
        atomicAdd(&oc[idx*4 + 0], f.x * inv);
        atomicAdd(&oc[idx*4 + 1], f.y * inv);
        atomicAdd(&oc[idx*4 + 2], f.z * inv);
        atomicAdd(&oc[idx*4 + 3], f.w * inv);
    }
#pragma unroll
    for (int off = 32; off > 0; off >>= 1)
        loss += __shfl_down(loss, off);
    if (lane == 0) partials[row] = loss;
}

__global__ void k_reduce(const float* __restrict__ partials,
                         float* __restrict__ out_loss) {
    __shared__ float sm[4];
    const int tid  = threadIdx.x;     // 256 threads = 4 waves
    const int lane = tid & 63;
    const int wav  = tid >> 6;
    float s = 0.0f;
    for (int i = tid; i < B; i += 256) s += partials[i];
#pragma unroll
    for (int off = 32; off > 0; off >>= 1)
        s += __shfl_down(s, off);
    if (lane == 0) sm[wav] = s;
    __syncthreads();
    if (tid == 0) {
        float t = sm[0] + sm[1] + sm[2] + sm[3];
        out_loss[0] = t / (float)B;
    }
}

extern "C" void kernel_launch(void* const* d_in, const int* in_sizes, int n_in,
                              void* d_out, int out_size, void* d_ws, size_t ws_size,
                              hipStream_t stream) {
    const float* features = (const float*)d_in[0];
    const int*   labels   = (const int*)d_in[1];
    const float* centers  = (const float*)d_in[2];

    float* out      = (float*)d_out;
    float* out_loss = out;            // d_out[0]
    float* outc     = out + 1;        // new_centers, 25.6M f32

    float* counts   = (float*)d_ws;           // NCLS f32
    float* partials = counts + NCLS;          // B f32

    hipMemsetAsync(counts, 0, NCLS * sizeof(float), stream);
    k_count<<<(B + 255) / 256, 256, 0, stream>>>(labels, counts);
    k_base<<<4096, 256, 0, stream>>>(centers, counts, outc);
    k_row<<<B, 64, 0, stream>>>(features, labels, centers, counts, outc, partials);
    k_reduce<<<1, 256, 0, stream>>>(partials, out_loss);
}